// Round 11
// baseline (118.280 us; speedup 1.0000x reference)
//
#include <hip/hip_runtime.h>
#include <hip/hip_fp16.h>
#include <math.h>

// Problem constants (fixed by reference)
#define NI_TOT 100000
#define NJ_TOT 100000
#define DD 8
#define SI_N 6000
#define SJ_N 6000
#define NNZ_N 500000
#define EPSF 1e-6f
#define LOG2E 1.44269504088896f

// Dense geometry: block = 64 i-rows (LDS) x 512 j-cols (2/thread in regs).
#define TI 64
#define JPT 2
#define JTILE (256 * JPT)                     // 512
#define ND_I ((SI_N + TI - 1) / TI)           // 94
#define NJT ((SJ_N + JTILE - 1) / JTILE)      // 12
#define N_DENSE_BLOCKS (ND_I * NJT)           // 1128
// Sparse: 2 links per thread (R8 best-measured config)
#define LPT 2
#define SPARSE_SPAN (256 * LPT)               // 512
#define N_SPARSE_BLOCKS ((NNZ_N + SPARSE_SPAN - 1) / SPARSE_SPAN) // 977
#define N_TOTAL_BLOCKS (N_DENSE_BLOCKS + N_SPARSE_BLOCKS)         // 2105

// Workspace layout: [fp16 z rows 16B each][fp16 biases]
#define NROWS (NI_TOT + NJ_TOT)
#define HZ_BYTES ((size_t)NROWS * DD * 2)     // 3.2 MB
#define HB_BYTES ((size_t)NROWS * 2)          // 400 KB

// A&S 6.1.36: Gamma(1+x) = 1 + a1 x + ... + a8 x^8, 0<=x<=1, |eps|<=3e-7
#define GA1 (-0.577191652f)
#define GA2 ( 0.988205891f)
#define GA3 (-0.897056937f)
#define GA4 ( 0.918206857f)
#define GA5 (-0.756704078f)
#define GA6 ( 0.482199394f)
#define GA7 (-0.193527818f)
#define GA8 ( 0.035868343f)

// ---- prep: pack z rows (16B/row) + biases to fp16; zero the output accum ----
__global__ __launch_bounds__(256) void pack_kernel(
    const float* __restrict__ beta, const float* __restrict__ gamma,
    const float* __restrict__ zi_all, const float* __restrict__ zj_all,
    __half* __restrict__ hz, __half* __restrict__ hb, float* __restrict__ out)
{
    const int r = blockIdx.x * 256 + threadIdx.x;
    if (r == 0) out[0] = 0.0f;   // replaces a whole hipMemsetAsync dispatch
    if (r < NROWS) {
        const float* src = (r < NI_TOT) ? zi_all + (size_t)r * DD
                                        : zj_all + (size_t)(r - NI_TOT) * DD;
        float4 a = ((const float4*)src)[0];
        float4 b = ((const float4*)src)[1];
        __half2 h0 = __floats2half2_rn(a.x, a.y);
        __half2 h1 = __floats2half2_rn(a.z, a.w);
        __half2 h2 = __floats2half2_rn(b.x, b.y);
        __half2 h3 = __floats2half2_rn(b.z, b.w);
        uint4 u;
        u.x = *(unsigned*)&h0; u.y = *(unsigned*)&h1;
        u.z = *(unsigned*)&h2; u.w = *(unsigned*)&h3;
        ((uint4*)hz)[r] = u;
    } else if (r < 2 * NROWS) {
        const int q = r - NROWS;
        float v = (q < NI_TOT) ? beta[q] : gamma[q - NI_TOT];
        hb[q] = __float2half(v);
    }
}

__device__ __forceinline__ void unpack_row(uint4 u, float f[DD]) {
    float2 p;
    p = __half22float2(*(__half2*)&u.x); f[0] = p.x; f[1] = p.y;
    p = __half22float2(*(__half2*)&u.y); f[2] = p.x; f[3] = p.y;
    p = __half22float2(*(__half2*)&u.z); f[4] = p.x; f[5] = p.y;
    p = __half22float2(*(__half2*)&u.w); f[6] = p.x; f[7] = p.y;
}

// NOTE (R9 lesson): NO __threadfence / acquire-release agent atomics here —
// agent-scope acquire emits buffer_inv sc1 (per-XCD L2 invalidate) per block,
// evicting the L2-resident fp16 table (tripled kernel time). Plain
// device-scope atomicAdd is memory-side and cache-neutral.
// R11: dense path also gathers from the fp16 table (16B/row, L2-resident)
// instead of f32 rows — dense j-gathers were the dominant L2-miss traffic.
__global__ __launch_bounds__(256) void fused_kernel(
    const float* __restrict__ beta, const float* __restrict__ gamma,
    const float* __restrict__ zi_all, const float* __restrict__ zj_all,
    const float* __restrict__ valueC,
    const int* __restrict__ si, const int* __restrict__ sj,       // dense samples
    const int* __restrict__ spi, const int* __restrict__ spj,     // sparse links
    const __half* __restrict__ hz, const __half* __restrict__ hb, // fp16 packed
    float* __restrict__ out, int mode)                            // 0=fp16, 1=f32 fallback
{
    __shared__ float sRed[4];
    const int t = threadIdx.x;
    const uint4* hzv = (const uint4*)hz;

    float blocksum = 0.0f;  // signed contribution of this block to LL

    if (blockIdx.x < N_DENSE_BLOCKS) {
        // -------- dense non-link: -sum(exp(beta_i + gamma_j - |zi-zj|)) --------
        // Everything pre-scaled by LOG2E so v_exp_f32 (exp2) applies directly.
        __shared__ __align__(16) float  sZi[TI * DD]; // (zi+EPS)*LOG2E, row-major
        __shared__ __align__(8)  float2 sIB[TI];      // {|ziL|^2, beta*LOG2E}

        const int it = blockIdx.x % ND_I;
        const int js = blockIdx.x / ND_I;
        const int i0 = it * TI;

        // Stage i-tile: one uint4 gather per row (fp16 path) by threads t<64.
        if (mode == 0) {
            if (t < TI) {
                int gi = i0 + t;
                float f[DD];
                float s = 0.0f, bL = -1e30f;
                if (gi < SI_N) {
                    int row = si[gi];
                    unpack_row(hzv[row], f);
                    bL = __half2float(hb[row]) * LOG2E;
                } else {
#pragma unroll
                    for (int d = 0; d < DD; ++d) f[d] = 0.0f;
                }
#pragma unroll
                for (int d = 0; d < DD; ++d) {
                    float v = (f[d] + EPSF) * LOG2E;
                    sZi[t * DD + d] = v;
                    s = fmaf(v, v, s);
                }
                sIB[t] = make_float2(s, bL);
            }
        } else {
            for (int idx = t; idx < TI * DD; idx += 256) {
                int r = idx >> 3, d = idx & 7;
                int gi = i0 + r;
                float v = (gi < SI_N) ? zi_all[(size_t)si[gi] * DD + d] : 0.0f;
                sZi[idx] = (v + EPSF) * LOG2E;
            }
            __syncthreads();
            if (t < TI) {
                int gi = i0 + t;
                float s = 0.0f;
#pragma unroll
                for (int d = 0; d < DD; ++d) {
                    float v = sZi[t * DD + d];
                    s = fmaf(v, v, s);
                }
                float bL = (gi < SI_N) ? beta[si[gi]] * LOG2E : -1e30f;
                sIB[t] = make_float2(s, bL);
            }
        }

        // Gather this thread's 2 j-columns into registers.
        const int jb = js * JTILE + t * JPT;
        float zA[DD], zB[DD], glA, glB, s2A, s2B;
        {
            int gj = jb;
            if (gj < SJ_N) {
                int row = sj[gj];
                if (mode == 0) {
                    float f[DD];
                    unpack_row(hzv[NI_TOT + row], f);
#pragma unroll
                    for (int d = 0; d < DD; ++d) zA[d] = f[d] * LOG2E;
                    glA = __half2float(hb[NI_TOT + row]) * LOG2E;
                } else {
                    const float4* q = (const float4*)(zj_all + (size_t)row * DD);
                    float4 q0 = q[0], q1 = q[1];
                    zA[0]=q0.x*LOG2E; zA[1]=q0.y*LOG2E; zA[2]=q0.z*LOG2E; zA[3]=q0.w*LOG2E;
                    zA[4]=q1.x*LOG2E; zA[5]=q1.y*LOG2E; zA[6]=q1.z*LOG2E; zA[7]=q1.w*LOG2E;
                    glA = gamma[row] * LOG2E;
                }
            } else {
#pragma unroll
                for (int d = 0; d < DD; ++d) zA[d] = 0.0f;
                glA = -1e30f;
            }
            gj = jb + 1;
            if (gj < SJ_N) {
                int row = sj[gj];
                if (mode == 0) {
                    float f[DD];
                    unpack_row(hzv[NI_TOT + row], f);
#pragma unroll
                    for (int d = 0; d < DD; ++d) zB[d] = f[d] * LOG2E;
                    glB = __half2float(hb[NI_TOT + row]) * LOG2E;
                } else {
                    const float4* q = (const float4*)(zj_all + (size_t)row * DD);
                    float4 q0 = q[0], q1 = q[1];
                    zB[0]=q0.x*LOG2E; zB[1]=q0.y*LOG2E; zB[2]=q0.z*LOG2E; zB[3]=q0.w*LOG2E;
                    zB[4]=q1.x*LOG2E; zB[5]=q1.y*LOG2E; zB[6]=q1.z*LOG2E; zB[7]=q1.w*LOG2E;
                    glB = gamma[row] * LOG2E;
                }
            } else {
#pragma unroll
                for (int d = 0; d < DD; ++d) zB[d] = 0.0f;
                glB = -1e30f;
            }
            float sa = 0.0f, sb = 0.0f;
#pragma unroll
            for (int d = 0; d < DD; ++d) {
                sa = fmaf(zA[d], zA[d], sa);
                sb = fmaf(zB[d], zB[d], sb);
            }
            s2A = sa; s2B = sb;
        }
        __syncthreads();  // sZi + sIB ready

        // ---- hot loop: 64 i-rows, barrier-free, row rotated 1 ahead ----
        float acc0 = 0.0f, acc1 = 0.0f;
        float4 cr0 = *(const float4*)&sZi[0];
        float4 cr1 = *(const float4*)&sZi[4];
        float2 cib = sIB[0];
#pragma unroll 4
        for (int a = 0; a < TI; ++a) {
            float4 nr0, nr1; float2 nib;
            if (a + 1 < TI) {              // prefetch next row (broadcast ds_read)
                nr0 = *(const float4*)&sZi[(a + 1) * DD];
                nr1 = *(const float4*)&sZi[(a + 1) * DD + 4];
                nib = sIB[a + 1];
            }
            float dA = 0.0f, dB = 0.0f;
            dA = fmaf(cr0.x, zA[0], dA); dB = fmaf(cr0.x, zB[0], dB);
            dA = fmaf(cr0.y, zA[1], dA); dB = fmaf(cr0.y, zB[1], dB);
            dA = fmaf(cr0.z, zA[2], dA); dB = fmaf(cr0.z, zB[2], dB);
            dA = fmaf(cr0.w, zA[3], dA); dB = fmaf(cr0.w, zB[3], dB);
            dA = fmaf(cr1.x, zA[4], dA); dB = fmaf(cr1.x, zB[4], dB);
            dA = fmaf(cr1.y, zA[5], dA); dB = fmaf(cr1.y, zB[5], dB);
            dA = fmaf(cr1.z, zA[6], dA); dB = fmaf(cr1.z, zB[6], dB);
            dA = fmaf(cr1.w, zA[7], dA); dB = fmaf(cr1.w, zB[7], dB);
            // distL^2 = |ziL|^2 + |zjL|^2 - 2 ziL.zjL  (pre-scaled by log2e)
            float ssA = fmaf(dA, -2.0f, cib.x + s2A);
            float ssB = fmaf(dB, -2.0f, cib.x + s2B);
            ssA = fmaxf(ssA, 1e-20f);
            ssB = fmaxf(ssB, 1e-20f);
            float xA = cib.y + glA - __builtin_amdgcn_sqrtf(ssA);
            float xB = cib.y + glB - __builtin_amdgcn_sqrtf(ssB);
            acc0 += __builtin_amdgcn_exp2f(xA);
            acc1 += __builtin_amdgcn_exp2f(xB);
            cr0 = nr0; cr1 = nr1; cib = nib;
        }
        blocksum = -(acc0 + acc1);   // dense term enters LL negatively
    } else {
        // ---------------- sparse link term: Poisson log-likelihood ----------------
        const int base = (blockIdx.x - N_DENSE_BLOCKS) * SPARSE_SPAN + t;
        float val = 0.0f;
#pragma unroll
        for (int u = 0; u < LPT; ++u) {
            const int idx = base + u * 256;
            if (idx >= NNZ_N) continue;
            const int i = spi[idx], j = spj[idx];
            const float c = valueC[idx];
            float dist, bg;
            if (mode == 0) {
                // fp16 packed path: 16B/row gathers, L2-resident per XCD
                uint4 ui = hzv[i];
                uint4 uj = hzv[NI_TOT + j];
                float fi[DD], fj[DD];
                unpack_row(ui, fi);
                unpack_row(uj, fj);
                float ss = 0.0f;
#pragma unroll
                for (int d = 0; d < DD; ++d) {
                    float df = fi[d] - fj[d] + EPSF;
                    ss = fmaf(df, df, ss);
                }
                ss = fmaxf(ss, 1e-20f);
                dist = __builtin_amdgcn_sqrtf(ss);
                bg = __half2float(hb[i]) + __half2float(hb[NI_TOT + j]);
            } else {
                // f32 fallback (no workspace)
                const float4* zi4 = (const float4*)(zi_all + (size_t)i * DD);
                const float4* zj4 = (const float4*)(zj_all + (size_t)j * DD);
                float4 a0 = zi4[0], a1 = zi4[1];
                float4 b0 = zj4[0], b1 = zj4[1];
                float ss = 0.0f, df;
                df = a0.x-b0.x+EPSF; ss = fmaf(df,df,ss);
                df = a0.y-b0.y+EPSF; ss = fmaf(df,df,ss);
                df = a0.z-b0.z+EPSF; ss = fmaf(df,df,ss);
                df = a0.w-b0.w+EPSF; ss = fmaf(df,df,ss);
                df = a1.x-b1.x+EPSF; ss = fmaf(df,df,ss);
                df = a1.y-b1.y+EPSF; ss = fmaf(df,df,ss);
                df = a1.z-b1.z+EPSF; ss = fmaf(df,df,ss);
                df = a1.w-b1.w+EPSF; ss = fmaf(df,df,ss);
                ss = fmaxf(ss, 1e-20f);
                dist = __builtin_amdgcn_sqrtf(ss);
                bg = beta[i] + gamma[j];
            }
            // gammaln(c+1) via A&S 6.1.36 poly (|e|<=3e-7), ln = log2/log2e
            float g = 1.0f + c*(GA1 + c*(GA2 + c*(GA3 + c*(GA4 + c*(GA5
                          + c*(GA6 + c*(GA7 + c*GA8)))))));
            val += c * (bg - dist) - __builtin_amdgcn_logf(g) * (1.0f / LOG2E);
        }
        blocksum = val;  // positive sign
    }

    // Block reduction: wave shuffle, cross-wave via LDS, one atomic per block.
    float acc = blocksum;
#pragma unroll
    for (int off = 32; off; off >>= 1) acc += __shfl_down(acc, off, 64);
    const int lane = t & 63, w = t >> 6;
    if (lane == 0) sRed[w] = acc;
    __syncthreads();
    if (t == 0) atomicAdd(out, sRed[0] + sRed[1] + sRed[2] + sRed[3]);
}

extern "C" void kernel_launch(void* const* d_in, const int* in_sizes, int n_in,
                              void* d_out, int out_size, void* d_ws, size_t ws_size,
                              hipStream_t stream) {
    const float* beta   = (const float*)d_in[0];
    const float* gamma  = (const float*)d_in[1];
    const float* zi     = (const float*)d_in[2];
    const float* zj     = (const float*)d_in[3];
    const float* valueC = (const float*)d_in[4];
    const int* si   = (const int*)d_in[5];
    const int* sjx  = (const int*)d_in[6];
    const int* spi  = (const int*)d_in[7];
    const int* spj  = (const int*)d_in[8];
    float* out = (float*)d_out;

    const size_t need = HZ_BYTES + HB_BYTES;

    if (ws_size >= need) {
        __half* hz = (__half*)d_ws;
        __half* hb = (__half*)((char*)d_ws + HZ_BYTES);
        const int packb = (2 * NROWS + 255) / 256;      // 1563
        pack_kernel<<<packb, 256, 0, stream>>>(beta, gamma, zi, zj, hz, hb, out);
        fused_kernel<<<N_TOTAL_BLOCKS, 256, 0, stream>>>(
            beta, gamma, zi, zj, valueC, si, sjx, spi, spj, hz, hb, out, 0);
    } else {
        // Fallback: f32 path, no workspace use
        hipMemsetAsync(out, 0, sizeof(float), stream);
        fused_kernel<<<N_TOTAL_BLOCKS, 256, 0, stream>>>(
            beta, gamma, zi, zj, valueC, si, sjx, spi, spj,
            (const __half*)zi, (const __half*)zi, out, 1);
    }
}

// Round 12
// 111.792 us; speedup vs baseline: 1.0580x; 1.0580x over previous
//
#include <hip/hip_runtime.h>
#include <hip/hip_fp16.h>
#include <math.h>

// Problem constants (fixed by reference)
#define NI_TOT 100000
#define NJ_TOT 100000
#define DD 8
#define SI_N 6000
#define SJ_N 6000
#define NNZ_N 500000
#define EPSF 1e-6f
#define LOG2E 1.44269504088896f

// Dense geometry: block = 64 i-rows (LDS) x 512 j-cols (2/thread in regs).
#define TI 64
#define JPT 2
#define JTILE (256 * JPT)                     // 512
#define ND_I ((SI_N + TI - 1) / TI)           // 94
#define NJT ((SJ_N + JTILE - 1) / JTILE)      // 12
#define N_DENSE_BLOCKS (ND_I * NJT)           // 1128
// Sparse: 2 links per thread (R8 best-measured config)
#define LPT 2
#define SPARSE_SPAN (256 * LPT)               // 512
#define N_SPARSE_BLOCKS ((NNZ_N + SPARSE_SPAN - 1) / SPARSE_SPAN) // 977
#define N_TOTAL_BLOCKS (N_DENSE_BLOCKS + N_SPARSE_BLOCKS)         // 2105

// Workspace layout: [fp16 z rows 16B each][fp16 biases][partials]
#define NROWS (NI_TOT + NJ_TOT)
#define HZ_BYTES ((size_t)NROWS * DD * 2)     // 3.2 MB
#define HB_BYTES ((size_t)NROWS * 2)          // 400 KB
#define PARTIALS_OFF (HZ_BYTES + HB_BYTES)

// A&S 6.1.36: Gamma(1+x) = 1 + a1 x + ... + a8 x^8, 0<=x<=1, |eps|<=3e-7
#define GA1 (-0.577191652f)
#define GA2 ( 0.988205891f)
#define GA3 (-0.897056937f)
#define GA4 ( 0.918206857f)
#define GA5 (-0.756704078f)
#define GA6 ( 0.482199394f)
#define GA7 (-0.193527818f)
#define GA8 ( 0.035868343f)

// ---- prep: pack z rows (16B/row) + biases to fp16 in workspace ----
__global__ __launch_bounds__(256) void pack_kernel(
    const float* __restrict__ beta, const float* __restrict__ gamma,
    const float* __restrict__ zi_all, const float* __restrict__ zj_all,
    __half* __restrict__ hz, __half* __restrict__ hb)
{
    const int r = blockIdx.x * 256 + threadIdx.x;
    if (r < NROWS) {
        const float* src = (r < NI_TOT) ? zi_all + (size_t)r * DD
                                        : zj_all + (size_t)(r - NI_TOT) * DD;
        float4 a = ((const float4*)src)[0];
        float4 b = ((const float4*)src)[1];
        __half2 h0 = __floats2half2_rn(a.x, a.y);
        __half2 h1 = __floats2half2_rn(a.z, a.w);
        __half2 h2 = __floats2half2_rn(b.x, b.y);
        __half2 h3 = __floats2half2_rn(b.z, b.w);
        uint4 u;
        u.x = *(unsigned*)&h0; u.y = *(unsigned*)&h1;
        u.z = *(unsigned*)&h2; u.w = *(unsigned*)&h3;
        ((uint4*)hz)[r] = u;
    } else if (r < 2 * NROWS) {
        const int q = r - NROWS;
        float v = (q < NI_TOT) ? beta[q] : gamma[q - NI_TOT];
        hb[q] = __float2half(v);
    }
}

__device__ __forceinline__ void unpack_row(uint4 u, float f[DD]) {
    float2 p;
    p = __half22float2(*(__half2*)&u.x); f[0] = p.x; f[1] = p.y;
    p = __half22float2(*(__half2*)&u.y); f[2] = p.x; f[3] = p.y;
    p = __half22float2(*(__half2*)&u.z); f[4] = p.x; f[5] = p.y;
    p = __half22float2(*(__half2*)&u.w); f[6] = p.x; f[7] = p.y;
}

// R9 lesson: NO __threadfence / agent-scope acq-rel atomics (per-XCD L2
// invalidate kills the L2-resident fp16 table). R11 lesson: dense gathers
// stay f32 (fp16 dense reads were a latency regression, not a BW win).
// R12: depth-2 row prefetch — ds_read latency ~120cyc > 80cyc/iter issue,
// so depth-1 rotation stalled every iteration on lgkmcnt.
__global__ __launch_bounds__(256) void fused_kernel(
    const float* __restrict__ beta, const float* __restrict__ gamma,
    const float* __restrict__ zi_all, const float* __restrict__ zj_all,
    const float* __restrict__ valueC,
    const int* __restrict__ si, const int* __restrict__ sj,       // dense samples
    const int* __restrict__ spi, const int* __restrict__ spj,     // sparse links
    const __half* __restrict__ hz, const __half* __restrict__ hb, // fp16 packed
    float* __restrict__ partials, float* __restrict__ out, int mode) // 0=ws, 1=atomic
{
    __shared__ float sRed[4];
    const int t = threadIdx.x;

    float blocksum = 0.0f;  // signed contribution of this block to LL

    if (blockIdx.x < N_DENSE_BLOCKS) {
        // -------- dense non-link: -sum(exp(beta_i + gamma_j - |zi-zj|)) --------
        // Everything pre-scaled by LOG2E so v_exp_f32 (exp2) applies directly.
        // +2 pad rows so the depth-2 prefetch needs no guard branch.
        __shared__ __align__(16) float  sZi[(TI + 2) * DD];
        __shared__ __align__(8)  float2 sIB[TI + 2];   // {|ziL|^2, beta*LOG2E}

        const int it = blockIdx.x % ND_I;
        const int js = blockIdx.x / ND_I;
        const int i0 = it * TI;

        // Stage i-tile (512 elems, 2/thread), f32 gathers (R8 style).
        for (int idx = t; idx < TI * DD; idx += 256) {
            int r = idx >> 3, d = idx & 7;
            int gi = i0 + r;
            float v = (gi < SI_N) ? zi_all[(size_t)si[gi] * DD + d] : 0.0f;
            sZi[idx] = (v + EPSF) * LOG2E;
        }
        __syncthreads();
        if (t < TI) {
            int gi = i0 + t;
            float s = 0.0f;
#pragma unroll
            for (int d = 0; d < DD; ++d) {
                float v = sZi[t * DD + d];
                s = fmaf(v, v, s);
            }
            float bL = (gi < SI_N) ? beta[si[gi]] * LOG2E : -1e30f; // pad -> exp=0
            sIB[t] = make_float2(s, bL);
        }

        // Gather this thread's 2 j-columns into registers (overlaps sIB wave).
        const int jb = js * JTILE + t * JPT;
        float zA[DD], zB[DD], glA, glB, s2A, s2B;
        {
            int gj = jb;
            if (gj < SJ_N) {
                int row = sj[gj];
                const float4* q = (const float4*)(zj_all + (size_t)row * DD);
                float4 q0 = q[0], q1 = q[1];
                zA[0]=q0.x*LOG2E; zA[1]=q0.y*LOG2E; zA[2]=q0.z*LOG2E; zA[3]=q0.w*LOG2E;
                zA[4]=q1.x*LOG2E; zA[5]=q1.y*LOG2E; zA[6]=q1.z*LOG2E; zA[7]=q1.w*LOG2E;
                glA = gamma[row] * LOG2E;
            } else {
#pragma unroll
                for (int d = 0; d < DD; ++d) zA[d] = 0.0f;
                glA = -1e30f;
            }
            gj = jb + 1;
            if (gj < SJ_N) {
                int row = sj[gj];
                const float4* q = (const float4*)(zj_all + (size_t)row * DD);
                float4 q0 = q[0], q1 = q[1];
                zB[0]=q0.x*LOG2E; zB[1]=q0.y*LOG2E; zB[2]=q0.z*LOG2E; zB[3]=q0.w*LOG2E;
                zB[4]=q1.x*LOG2E; zB[5]=q1.y*LOG2E; zB[6]=q1.z*LOG2E; zB[7]=q1.w*LOG2E;
                glB = gamma[row] * LOG2E;
            } else {
#pragma unroll
                for (int d = 0; d < DD; ++d) zB[d] = 0.0f;
                glB = -1e30f;
            }
            float sa = 0.0f, sb = 0.0f;
#pragma unroll
            for (int d = 0; d < DD; ++d) {
                sa = fmaf(zA[d], zA[d], sa);
                sb = fmaf(zB[d], zB[d], sb);
            }
            s2A = sa; s2B = sb;
        }
        __syncthreads();  // sZi + sIB ready

        // ---- hot loop: 64 i-rows, barrier-free, DEPTH-2 row prefetch ----
        float acc0 = 0.0f, acc1 = 0.0f;
        float4 c0 = *(const float4*)&sZi[0];
        float4 c1 = *(const float4*)&sZi[4];
        float2 cb = sIB[0];
        float4 n0 = *(const float4*)&sZi[DD];
        float4 n1 = *(const float4*)&sZi[DD + 4];
        float2 nb = sIB[1];
#pragma unroll 4
        for (int a = 0; a < TI; ++a) {
            // issue row a+2 (pad rows make this always safe; results unused
            // past a=TI-1). 2 iterations of cover for ~120cyc LDS latency.
            float4 p0 = *(const float4*)&sZi[(a + 2) * DD];
            float4 p1 = *(const float4*)&sZi[(a + 2) * DD + 4];
            float2 pb = sIB[a + 2];
            float dA = 0.0f, dB = 0.0f;
            dA = fmaf(c0.x, zA[0], dA); dB = fmaf(c0.x, zB[0], dB);
            dA = fmaf(c0.y, zA[1], dA); dB = fmaf(c0.y, zB[1], dB);
            dA = fmaf(c0.z, zA[2], dA); dB = fmaf(c0.z, zB[2], dB);
            dA = fmaf(c0.w, zA[3], dA); dB = fmaf(c0.w, zB[3], dB);
            dA = fmaf(c1.x, zA[4], dA); dB = fmaf(c1.x, zB[4], dB);
            dA = fmaf(c1.y, zA[5], dA); dB = fmaf(c1.y, zB[5], dB);
            dA = fmaf(c1.z, zA[6], dA); dB = fmaf(c1.z, zB[6], dB);
            dA = fmaf(c1.w, zA[7], dA); dB = fmaf(c1.w, zB[7], dB);
            // distL^2 = |ziL|^2 + |zjL|^2 - 2 ziL.zjL  (pre-scaled by log2e)
            float ssA = fmaf(dA, -2.0f, cb.x + s2A);
            float ssB = fmaf(dB, -2.0f, cb.x + s2B);
            ssA = fmaxf(ssA, 1e-20f);
            ssB = fmaxf(ssB, 1e-20f);
            float xA = cb.y + glA - __builtin_amdgcn_sqrtf(ssA);
            float xB = cb.y + glB - __builtin_amdgcn_sqrtf(ssB);
            acc0 += __builtin_amdgcn_exp2f(xA);
            acc1 += __builtin_amdgcn_exp2f(xB);
            c0 = n0; c1 = n1; cb = nb;
            n0 = p0; n1 = p1; nb = pb;
        }
        blocksum = -(acc0 + acc1);   // dense term enters LL negatively
    } else {
        // ---------------- sparse link term: Poisson log-likelihood ----------------
        const int base = (blockIdx.x - N_DENSE_BLOCKS) * SPARSE_SPAN + t;
        float val = 0.0f;
        const uint4* hzv = (const uint4*)hz;
#pragma unroll
        for (int u = 0; u < LPT; ++u) {
            const int idx = base + u * 256;
            if (idx >= NNZ_N) continue;
            const int i = spi[idx], j = spj[idx];
            const float c = valueC[idx];
            float dist, bg;
            if (mode == 0) {
                // fp16 packed path: 16B/row gathers, L2-resident per XCD
                uint4 ui = hzv[i];
                uint4 uj = hzv[NI_TOT + j];
                float fi[DD], fj[DD];
                unpack_row(ui, fi);
                unpack_row(uj, fj);
                float ss = 0.0f;
#pragma unroll
                for (int d = 0; d < DD; ++d) {
                    float df = fi[d] - fj[d] + EPSF;
                    ss = fmaf(df, df, ss);
                }
                ss = fmaxf(ss, 1e-20f);
                dist = __builtin_amdgcn_sqrtf(ss);
                bg = __half2float(hb[i]) + __half2float(hb[NI_TOT + j]);
            } else {
                // f32 fallback (no workspace)
                const float4* zi4 = (const float4*)(zi_all + (size_t)i * DD);
                const float4* zj4 = (const float4*)(zj_all + (size_t)j * DD);
                float4 a0 = zi4[0], a1 = zi4[1];
                float4 b0 = zj4[0], b1 = zj4[1];
                float ss = 0.0f, df;
                df = a0.x-b0.x+EPSF; ss = fmaf(df,df,ss);
                df = a0.y-b0.y+EPSF; ss = fmaf(df,df,ss);
                df = a0.z-b0.z+EPSF; ss = fmaf(df,df,ss);
                df = a0.w-b0.w+EPSF; ss = fmaf(df,df,ss);
                df = a1.x-b1.x+EPSF; ss = fmaf(df,df,ss);
                df = a1.y-b1.y+EPSF; ss = fmaf(df,df,ss);
                df = a1.z-b1.z+EPSF; ss = fmaf(df,df,ss);
                df = a1.w-b1.w+EPSF; ss = fmaf(df,df,ss);
                ss = fmaxf(ss, 1e-20f);
                dist = __builtin_amdgcn_sqrtf(ss);
                bg = beta[i] + gamma[j];
            }
            // gammaln(c+1) via A&S 6.1.36 poly (|e|<=3e-7), ln = log2/log2e
            float g = 1.0f + c*(GA1 + c*(GA2 + c*(GA3 + c*(GA4 + c*(GA5
                          + c*(GA6 + c*(GA7 + c*GA8)))))));
            val += c * (bg - dist) - __builtin_amdgcn_logf(g) * (1.0f / LOG2E);
        }
        blocksum = val;  // positive sign
    }

    // Block reduction: wave shuffle then cross-wave via LDS
    float acc = blocksum;
#pragma unroll
    for (int off = 32; off; off >>= 1) acc += __shfl_down(acc, off, 64);
    const int lane = t & 63, w = t >> 6;
    if (lane == 0) sRed[w] = acc;
    __syncthreads();
    if (t == 0) {
        float s = sRed[0] + sRed[1] + sRed[2] + sRed[3];
        if (mode) atomicAdd(out, s);
        else partials[blockIdx.x] = s;
    }
}

__global__ __launch_bounds__(256) void final_reduce_kernel(
    const float* __restrict__ p, int n, float* __restrict__ out)
{
    __shared__ float sRed[4];
    float s0 = 0.0f, s1 = 0.0f, s2 = 0.0f, s3 = 0.0f;
    int i = threadIdx.x;
    for (; i + 768 < n; i += 1024) {      // 4 independent chains to pipeline loads
        s0 += p[i]; s1 += p[i + 256]; s2 += p[i + 512]; s3 += p[i + 768];
    }
    for (; i < n; i += 256) s0 += p[i];
    float s = (s0 + s1) + (s2 + s3);
#pragma unroll
    for (int off = 32; off; off >>= 1) s += __shfl_down(s, off, 64);
    const int lane = threadIdx.x & 63, w = threadIdx.x >> 6;
    if (lane == 0) sRed[w] = s;
    __syncthreads();
    if (threadIdx.x == 0) out[0] = sRed[0] + sRed[1] + sRed[2] + sRed[3];
}

extern "C" void kernel_launch(void* const* d_in, const int* in_sizes, int n_in,
                              void* d_out, int out_size, void* d_ws, size_t ws_size,
                              hipStream_t stream) {
    const float* beta   = (const float*)d_in[0];
    const float* gamma  = (const float*)d_in[1];
    const float* zi     = (const float*)d_in[2];
    const float* zj     = (const float*)d_in[3];
    const float* valueC = (const float*)d_in[4];
    const int* si   = (const int*)d_in[5];
    const int* sjx  = (const int*)d_in[6];
    const int* spi  = (const int*)d_in[7];
    const int* spj  = (const int*)d_in[8];
    float* out = (float*)d_out;

    const int ntot = N_TOTAL_BLOCKS;
    const size_t need = PARTIALS_OFF + (size_t)ntot * sizeof(float);

    if (ws_size >= need) {
        __half* hz = (__half*)d_ws;
        __half* hb = (__half*)((char*)d_ws + HZ_BYTES);
        float* p   = (float*)((char*)d_ws + PARTIALS_OFF);
        const int packb = (2 * NROWS + 255) / 256;      // 1563
        pack_kernel<<<packb, 256, 0, stream>>>(beta, gamma, zi, zj, hz, hb);
        fused_kernel<<<ntot, 256, 0, stream>>>(
            beta, gamma, zi, zj, valueC, si, sjx, spi, spj, hz, hb, p, out, 0);
        final_reduce_kernel<<<1, 256, 0, stream>>>(p, ntot, out);
    } else {
        // Fallback: f32 sparse + atomic accumulation directly into d_out
        hipMemsetAsync(out, 0, sizeof(float), stream);
        fused_kernel<<<ntot, 256, 0, stream>>>(
            beta, gamma, zi, zj, valueC, si, sjx, spi, spj,
            (const __half*)zi, (const __half*)zi, nullptr, out, 1);
    }
}